// Round 2
// baseline (175.536 us; speedup 1.0000x reference)
//
#include <hip/hip_runtime.h>

// NCC2D fused single-kernel: 5 box-sums (9x9, zero-pad) + cc + global mean.
// Thread owns 2 columns; horizontal 9-sums from global halo loads (L1/L2
// absorb the overlap); vertical 9-row running window in a register ring with
// static indices (inner loop unrolled by 9; NROWS=18=2*9).
// SH=10 -> 52 strips x 32 images = 1664 blocks (~6.5 blocks/CU) to fix the
// 21% occupancy seen at SH=28 (608 blocks).
// Final reduce fused: per-block atomicAdd into ws[0], completion counter in
// ws[1]; last block writes -mean. ws[0:1] zeroed via hipMemsetAsync (graph-
// capturable memset node).

#define BATCH   32
#define IMH     512
#define IMW     512
#define SH      10          // output rows per block
#define NSTRIP  52          // 52*10 = 520 >= 512 (tail masked)
#define NROWS   18          // SH + 8 halo rows; multiple of 9
#define NBLOCKS (BATCH * NSTRIP)

__global__ __launch_bounds__(256) void ncc_main(const float* __restrict__ I,
                                                const float* __restrict__ J,
                                                float* __restrict__ acc_ws,
                                                unsigned* __restrict__ cnt_ws,
                                                float* __restrict__ out) {
    const int t  = threadIdx.x;
    const int s  = blockIdx.x;   // strip
    const int b  = blockIdx.y;   // image
    const int r0 = s * SH;       // first output row of strip
    const float inv81 = 1.0f / 81.0f;

    const float* Ib = I + (size_t)b * IMH * IMW;
    const float* Jb = J + (size_t)b * IMH * IMW;

    const int cbase = 2 * t - 4; // leftmost halo column for this thread

    // ring[j][q]: horizontal sums H of the last 9 input rows, per quantity
    // q: 0=I 1=J 2=II 3=JJ 4=IJ ; .x = col 2t, .y = col 2t+1
    float2 ring[9][5];
#pragma unroll
    for (int j = 0; j < 9; ++j)
#pragma unroll
        for (int q = 0; q < 5; ++q) ring[j][q] = make_float2(0.f, 0.f);

    float2 V[5];
#pragma unroll
    for (int q = 0; q < 5; ++q) V[q] = make_float2(0.f, 0.f);

    float2 acc = make_float2(0.f, 0.f);

#pragma unroll 1
    for (int g = 0; g < 2; ++g) {
#pragma unroll
        for (int j = 0; j < 9; ++j) {
            const int i  = g * 9 + j;     // iteration 0..17
            const int ri = r0 - 4 + i;    // input row (may be OOB -> zeros)

            float vI[10], vJ[10];
            if ((unsigned)ri < (unsigned)IMH) {
                const float* rowI = Ib + (size_t)ri * IMW;
                const float* rowJ = Jb + (size_t)ri * IMW;
#pragma unroll
                for (int k = 0; k < 5; ++k) {
                    const int ck = cbase + 2 * k;   // even; pair never straddles edge
                    if ((unsigned)ck < (unsigned)IMW) {
                        float2 iv = *(const float2*)(rowI + ck);
                        float2 jv = *(const float2*)(rowJ + ck);
                        vI[2 * k] = iv.x; vI[2 * k + 1] = iv.y;
                        vJ[2 * k] = jv.x; vJ[2 * k + 1] = jv.y;
                    } else {
                        vI[2 * k] = 0.f; vI[2 * k + 1] = 0.f;
                        vJ[2 * k] = 0.f; vJ[2 * k + 1] = 0.f;
                    }
                }
            } else {
#pragma unroll
                for (int m = 0; m < 10; ++m) { vI[m] = 0.f; vJ[m] = 0.f; }
            }

            // horizontal 9-window sums for the two owned columns
            float sI = 0.f, sJ = 0.f, sII = 0.f, sJJ = 0.f, sIJ = 0.f;
#pragma unroll
            for (int m = 0; m < 9; ++m) {
                sI  += vI[m];
                sJ  += vJ[m];
                sII += vI[m] * vI[m];
                sJJ += vJ[m] * vJ[m];
                sIJ += vI[m] * vJ[m];
            }
            const float i0 = vI[0], j0 = vJ[0], i9 = vI[9], j9 = vJ[9];
            float2 Hn[5];
            Hn[0] = make_float2(sI,  sI  + i9      - i0);
            Hn[1] = make_float2(sJ,  sJ  + j9      - j0);
            Hn[2] = make_float2(sII, sII + i9 * i9 - i0 * i0);
            Hn[3] = make_float2(sJJ, sJJ + j9 * j9 - j0 * j0);
            Hn[4] = make_float2(sIJ, sIJ + i9 * j9 - i0 * j0);

            // vertical running window: V = sum of last 9 H rows
#pragma unroll
            for (int q = 0; q < 5; ++q) {
                const float2 old = ring[j][q];
                ring[j][q] = Hn[q];
                V[q].x += Hn[q].x - old.x;
                V[q].y += Hn[q].y - old.y;
            }

            // emit output row r = ri - 4 once 9 rows accumulated
            if (i >= 8) {
                const int r = r0 + i - 8;
                if (r < IMH) {
                    {
                        const float aI = V[0].x, aJ = V[1].x;
                        const float cross = V[4].x - aI * aJ * inv81;
                        const float iv    = V[2].x - aI * aI * inv81;
                        const float jv    = V[3].x - aJ * aJ * inv81;
                        acc.x += cross * cross *
                                 __builtin_amdgcn_rcpf(iv * jv + 1e-5f);
                    }
                    {
                        const float aI = V[0].y, aJ = V[1].y;
                        const float cross = V[4].y - aI * aJ * inv81;
                        const float iv    = V[2].y - aI * aI * inv81;
                        const float jv    = V[3].y - aJ * aJ * inv81;
                        acc.y += cross * cross *
                                 __builtin_amdgcn_rcpf(iv * jv + 1e-5f);
                    }
                }
            }
        }
    }

    // block reduction: wave shuffle, then LDS across the 4 waves
    float sum = acc.x + acc.y;
#pragma unroll
    for (int off = 32; off > 0; off >>= 1) sum += __shfl_down(sum, off, 64);

    __shared__ float wsum[4];
    if ((t & 63) == 0) wsum[t >> 6] = sum;
    __syncthreads();
    if (t == 0) {
        const float bsum = wsum[0] + wsum[1] + wsum[2] + wsum[3];
        atomicAdd(acc_ws, bsum);          // device-scope
        __threadfence();
        const unsigned old = atomicAdd(cnt_ws, 1u);
        if (old == (unsigned)(NBLOCKS - 1)) {
            const float total = atomicAdd(acc_ws, 0.0f);  // coherent read
            out[0] = -total / 8388608.0f;                 // -mean over 32*512*512
        }
    }
}

extern "C" void kernel_launch(void* const* d_in, const int* in_sizes, int n_in,
                              void* d_out, int out_size, void* d_ws, size_t ws_size,
                              hipStream_t stream) {
    const float* I = (const float*)d_in[0];  // y_true
    const float* J = (const float*)d_in[1];  // y_pred
    float* acc_ws  = (float*)d_ws;           // ws[0]: running sum
    unsigned* cnt  = (unsigned*)d_ws + 1;    // ws[1]: completion counter
    float* out     = (float*)d_out;

    hipMemsetAsync(d_ws, 0, 2 * sizeof(float), stream);

    dim3 grid(NSTRIP, BATCH);
    ncc_main<<<grid, 256, 0, stream>>>(I, J, acc_ws, cnt, out);
}

// Round 3
// 138.703 us; speedup vs baseline: 1.2656x; 1.2656x over previous
//
#include <hip/hip_runtime.h>

// NCC2D fused single-kernel, round-staged LDS version.
// Block = 256 threads, covers a full-width strip: SH=32 output rows (=> 40
// input rows = 5 rounds x 8). Grid = 16 strips x 32 images = 512 blocks =
// exactly 2 blocks/CU (launch_bounds(256,2): 8 waves/CU, VGPR cap 256).
//
// R2 post-mortem: at VGPR=72 the compiler latency-serialized 10 tiny 8B
// loads per row (~1 cache round-trip per row). Fix: burst staging — each
// thread issues 8 independent global_load_dwordx4 per round (I-half /
// J-half threads), written to padded LDS rows; horizontal windows read from
// LDS (ds_read_b64, no edge predication: +-4 zero pads). Vertical 9-row
// running window stays in a register ring with static indices (full 40-row
// unroll). Next round's loads overlap current round's compute.
//
// Finish: block reduce -> device atomicAdd + completion counter in d_ws
// (zeroed by hipMemsetAsync, graph-capturable); last block writes -mean.

#define BATCH   32
#define IMH     512
#define IMW     512
#define SH      32          // output rows per block
#define NSTRIP  16          // 16*32 = 512 exactly (no tail)
#define NROUND  5           // (SH+8)/8 input-row rounds
#define NBLOCKS (BATCH * NSTRIP)
#define LROW    520         // padded LDS row: [0..4)=0, [4..516)=data, [516..520)=0

__global__ __launch_bounds__(256, 2) void ncc_main(const float* __restrict__ I,
                                                   const float* __restrict__ J,
                                                   float* __restrict__ acc_ws,
                                                   unsigned* __restrict__ cnt_ws,
                                                   float* __restrict__ out) {
    __shared__ float ldsI[8 * LROW];
    __shared__ float ldsJ[8 * LROW];
    __shared__ float wsum[4];

    const int t  = threadIdx.x;
    const int s  = blockIdx.x;   // strip
    const int b  = blockIdx.y;   // image
    const int r0 = s * SH;       // first output row of strip
    const float inv81 = 1.0f / 81.0f;

    const float* Ib = I + (size_t)b * IMH * IMW;
    const float* Jb = J + (size_t)b * IMH * IMW;

    // staging role: threads 0..127 load I rows, 128..255 load J rows
    const int half = t >> 7;
    const int col  = 4 * (t & 127);              // float4 column of owned quarter-row
    const float* src = half ? Jb : Ib;
    float*       dst = half ? ldsJ : ldsI;

    float4 stage[8];
    const float4 zero4 = make_float4(0.f, 0.f, 0.f, 0.f);

    auto load_round = [&](int R) {
#pragma unroll
        for (int q = 0; q < 8; ++q) {
            const int ri = r0 - 4 + R * 8 + q;
            stage[q] = ((unsigned)ri < (unsigned)IMH)
                           ? *(const float4*)(src + (size_t)ri * IMW + col)
                           : zero4;
        }
    };

    load_round(0);

    // zero the +-4 pads of all 8 rows of both arrays (written once, never
    // overwritten: staging writes only [4..516))
    if (t < 128) {
        float* arr = (t >> 6) ? ldsJ : ldsI;
        const int idx = t & 63;             // 8 rows x 8 pad slots
        const int row = idx >> 3;
        const int k   = idx & 7;
        const int p   = (k < 4) ? k : (512 + k);
        arr[row * LROW + p] = 0.f;
    }
    __syncthreads();

    // ring[j][q]: horizontal sums H of the last 9 input rows
    // q: 0=I 1=J 2=II 3=JJ 4=IJ ; .x = col 2t, .y = col 2t+1
    float2 ring[9][5];
#pragma unroll
    for (int j = 0; j < 9; ++j)
#pragma unroll
        for (int q = 0; q < 5; ++q) ring[j][q] = make_float2(0.f, 0.f);

    float2 V[5];
#pragma unroll
    for (int q = 0; q < 5; ++q) V[q] = make_float2(0.f, 0.f);

    float2 acc = make_float2(0.f, 0.f);

#pragma unroll
    for (int R = 0; R < NROUND; ++R) {
        // commit this round's staged rows to LDS
#pragma unroll
        for (int q = 0; q < 8; ++q)
            *(float4*)(dst + q * LROW + 4 + col) = stage[q];
        __syncthreads();

        // overlap: issue next round's global loads over this round's compute
        if (R < NROUND - 1) load_round(R + 1);

#pragma unroll
        for (int q8 = 0; q8 < 8; ++q8) {
            const int i = R * 8 + q8;       // global row iteration 0..39
            const int j = i % 9;            // static ring slot

            float vI[10], vJ[10];
#pragma unroll
            for (int k = 0; k < 5; ++k) {
                const float2 a = *(const float2*)&ldsI[q8 * LROW + 2 * t + 2 * k];
                const float2 c = *(const float2*)&ldsJ[q8 * LROW + 2 * t + 2 * k];
                vI[2 * k] = a.x; vI[2 * k + 1] = a.y;
                vJ[2 * k] = c.x; vJ[2 * k + 1] = c.y;
            }

            // horizontal 9-window sums for the two owned columns
            float sI = 0.f, sJ = 0.f, sII = 0.f, sJJ = 0.f, sIJ = 0.f;
#pragma unroll
            for (int m = 0; m < 9; ++m) {
                sI  += vI[m];
                sJ  += vJ[m];
                sII += vI[m] * vI[m];
                sJJ += vJ[m] * vJ[m];
                sIJ += vI[m] * vJ[m];
            }
            const float i0 = vI[0], j0 = vJ[0], i9 = vI[9], j9 = vJ[9];
            float2 Hn[5];
            Hn[0] = make_float2(sI,  sI  + i9      - i0);
            Hn[1] = make_float2(sJ,  sJ  + j9      - j0);
            Hn[2] = make_float2(sII, sII + i9 * i9 - i0 * i0);
            Hn[3] = make_float2(sJJ, sJJ + j9 * j9 - j0 * j0);
            Hn[4] = make_float2(sIJ, sIJ + i9 * j9 - i0 * j0);

            // vertical running window: V = sum of last 9 H rows
#pragma unroll
            for (int q = 0; q < 5; ++q) {
                const float2 old = ring[j][q];
                ring[j][q] = Hn[q];
                V[q].x += Hn[q].x - old.x;
                V[q].y += Hn[q].y - old.y;
            }

            // emit output row r = r0 + i - 8 once 9 rows accumulated
            if (i >= 8) {
                {
                    const float aI = V[0].x, aJ = V[1].x;
                    const float cross = V[4].x - aI * aJ * inv81;
                    const float iv    = V[2].x - aI * aI * inv81;
                    const float jv    = V[3].x - aJ * aJ * inv81;
                    acc.x += cross * cross *
                             __builtin_amdgcn_rcpf(iv * jv + 1e-5f);
                }
                {
                    const float aI = V[0].y, aJ = V[1].y;
                    const float cross = V[4].y - aI * aJ * inv81;
                    const float iv    = V[2].y - aI * aI * inv81;
                    const float jv    = V[3].y - aJ * aJ * inv81;
                    acc.y += cross * cross *
                             __builtin_amdgcn_rcpf(iv * jv + 1e-5f);
                }
            }
        }
        __syncthreads();   // all reads of this round done before next commit
    }

    // block reduction: wave shuffle, then LDS across the 4 waves
    float sum = acc.x + acc.y;
#pragma unroll
    for (int off = 32; off > 0; off >>= 1) sum += __shfl_down(sum, off, 64);

    if ((t & 63) == 0) wsum[t >> 6] = sum;
    __syncthreads();
    if (t == 0) {
        const float bsum = wsum[0] + wsum[1] + wsum[2] + wsum[3];
        atomicAdd(acc_ws, bsum);          // device-scope
        __threadfence();
        const unsigned old = atomicAdd(cnt_ws, 1u);
        if (old == (unsigned)(NBLOCKS - 1)) {
            const float total = atomicAdd(acc_ws, 0.0f);  // coherent read
            out[0] = -total / 8388608.0f;                 // -mean over 32*512*512
        }
    }
}

extern "C" void kernel_launch(void* const* d_in, const int* in_sizes, int n_in,
                              void* d_out, int out_size, void* d_ws, size_t ws_size,
                              hipStream_t stream) {
    const float* I = (const float*)d_in[0];  // y_true
    const float* J = (const float*)d_in[1];  // y_pred
    float* acc_ws  = (float*)d_ws;           // ws[0]: running sum
    unsigned* cnt  = (unsigned*)d_ws + 1;    // ws[1]: completion counter
    float* out     = (float*)d_out;

    hipMemsetAsync(d_ws, 0, 2 * sizeof(float), stream);

    dim3 grid(NSTRIP, BATCH);
    ncc_main<<<grid, 256, 0, stream>>>(I, J, acc_ws, cnt, out);
}

// Round 4
// 125.028 us; speedup vs baseline: 1.4040x; 1.1094x over previous
//
#include <hip/hip_runtime.h>

// NCC2D fused single-kernel, async-DMA round-staged version.
// Block = 256 threads, full-width strip, SH=28 output rows -> 36 input rows
// = 4 rounds x 9. Rounds of NINE so the vertical ring slot is the literal
// inner-loop index (static indexing; R3's rounds-of-8 + i%9 sent ring[] to
// scratch: 80 MB WRITE_SIZE).
// Staging: __builtin_amdgcn_global_load_lds width=16 (no staging VGPRs).
// Wave w: arr = w>>1 (I/J), h = w&1 (half-row); lane covers 16 B -> LDS dest
// is wave-uniform base + lane*16 as required. Double-buffered 9-row tile
// (75 KB LDS, 2 blocks/CU); round R+1 DMA overlaps round R compute.
// Finish: block reduce -> device atomicAdd + completion counter in d_ws
// (zeroed by hipMemsetAsync); last block writes -mean.

#define BATCH   32
#define IMH     512
#define IMW     512
#define SH      28          // output rows per block
#define NSTRIP  19          // 19*28 = 532 >= 512 (tail masked)
#define NROUND  4           // 36 input rows = 4 rounds x 9
#define NBLOCKS (BATCH * NSTRIP)
#define LROW    520         // [0..4)=0, [4..516)=data, [516..520)=0
#define AROWS   36          // 2 buf x 2 arr x 9 rows
#define LDSZ    (AROWS * LROW)

__global__ __launch_bounds__(256, 2) void ncc_main(const float* __restrict__ I,
                                                   const float* __restrict__ J,
                                                   float* __restrict__ acc_ws,
                                                   unsigned* __restrict__ cnt_ws,
                                                   float* __restrict__ out) {
    __shared__ __align__(16) float lds[LDSZ];
    __shared__ float wsum[4];

    const int t    = threadIdx.x;
    const int lane = t & 63;
    const int w    = t >> 6;     // wave 0..3
    const int arr  = w >> 1;     // 0: stage I rows, 1: stage J rows
    const int h    = w & 1;      // half-row (256 floats)
    const int s    = blockIdx.x; // strip
    const int b    = blockIdx.y; // image
    const int r0   = s * SH;
    const float inv81 = 1.0f / 81.0f;

    const float* Ib = I + (size_t)b * IMH * IMW;
    const float* Jb = J + (size_t)b * IMH * IMW;
    const float* src = arr ? Jb : Ib;

    // row-base (in floats) of (buf, arr, q) LDS row
    auto lrow = [](int buf, int a, int q) {
        return ((buf * 2 + a) * 9 + q) * LROW;
    };

    // stage 9 rows of round R into buffer `buf` (async DMA; no wait here)
    auto dma_round = [&](int R, int buf) {
#pragma unroll
        for (int q = 0; q < 9; ++q) {
            const int ri = r0 - 4 + R * 9 + q;
            float* ldst = &lds[lrow(buf, arr, q) + 4 + h * 256];
            if ((unsigned)ri < (unsigned)IMH) {
                const float* gsrc = src + (size_t)ri * IMW + h * 256 + lane * 4;
                __builtin_amdgcn_global_load_lds(
                    (const __attribute__((address_space(1))) void*)gsrc,
                    (__attribute__((address_space(3))) void*)ldst,
                    16, 0, 0);
            } else {
                *(float4*)(ldst + lane * 4) = make_float4(0.f, 0.f, 0.f, 0.f);
            }
        }
    };

    // zero the +-4 pads of all 36 LDS rows (written once; DMA never touches)
    for (int idx = t; idx < AROWS * 8; idx += 256) {
        const int arow = idx >> 3;
        const int k    = idx & 7;
        lds[arow * LROW + ((k < 4) ? k : (512 + k))] = 0.f;
    }

    dma_round(0, 0);
    __syncthreads();   // drains DMA(0) + pad writes

    // ring[j][q]: horizontal sums H of the last 9 input rows
    // q: 0=I 1=J 2=II 3=JJ 4=IJ ; .x = col 2t, .y = col 2t+1
    float2 ring[9][5];
#pragma unroll
    for (int j = 0; j < 9; ++j)
#pragma unroll
        for (int q = 0; q < 5; ++q) ring[j][q] = make_float2(0.f, 0.f);

    float2 V[5];
#pragma unroll
    for (int q = 0; q < 5; ++q) V[q] = make_float2(0.f, 0.f);

    float2 acc = make_float2(0.f, 0.f);

#pragma unroll 1
    for (int R = 0; R < NROUND; ++R) {
        if (R + 1 < NROUND) dma_round(R + 1, (R + 1) & 1);

        const int baseI = lrow(R & 1, 0, 0) + 2 * t;
        const int baseJ = lrow(R & 1, 1, 0) + 2 * t;

#pragma unroll
        for (int j = 0; j < 9; ++j) {      // j IS the ring slot (static)
            const int i = R * 9 + j;       // row iteration 0..35

            float vI[10], vJ[10];
#pragma unroll
            for (int k = 0; k < 5; ++k) {
                const float2 a = *(const float2*)&lds[baseI + j * LROW + 2 * k];
                const float2 c = *(const float2*)&lds[baseJ + j * LROW + 2 * k];
                vI[2 * k] = a.x; vI[2 * k + 1] = a.y;
                vJ[2 * k] = c.x; vJ[2 * k + 1] = c.y;
            }

            // horizontal 9-window sums for the two owned columns
            float sI = 0.f, sJ = 0.f, sII = 0.f, sJJ = 0.f, sIJ = 0.f;
#pragma unroll
            for (int m = 0; m < 9; ++m) {
                sI  += vI[m];
                sJ  += vJ[m];
                sII += vI[m] * vI[m];
                sJJ += vJ[m] * vJ[m];
                sIJ += vI[m] * vJ[m];
            }
            const float i0 = vI[0], j0 = vJ[0], i9 = vI[9], j9 = vJ[9];
            float2 Hn[5];
            Hn[0] = make_float2(sI,  sI  + i9      - i0);
            Hn[1] = make_float2(sJ,  sJ  + j9      - j0);
            Hn[2] = make_float2(sII, sII + i9 * i9 - i0 * i0);
            Hn[3] = make_float2(sJJ, sJJ + j9 * j9 - j0 * j0);
            Hn[4] = make_float2(sIJ, sIJ + i9 * j9 - i0 * j0);

            // vertical running window: V = sum of last 9 H rows
#pragma unroll
            for (int q = 0; q < 5; ++q) {
                const float2 old = ring[j][q];
                ring[j][q] = Hn[q];
                V[q].x += Hn[q].x - old.x;
                V[q].y += Hn[q].y - old.y;
            }

            // emit output row r = r0 + i - 8 once 9 rows accumulated
            if (i >= 8 && (r0 + i - 8) < IMH) {
                {
                    const float aI = V[0].x, aJ = V[1].x;
                    const float cross = V[4].x - aI * aJ * inv81;
                    const float iv    = V[2].x - aI * aI * inv81;
                    const float jv    = V[3].x - aJ * aJ * inv81;
                    acc.x += cross * cross *
                             __builtin_amdgcn_rcpf(iv * jv + 1e-5f);
                }
                {
                    const float aI = V[0].y, aJ = V[1].y;
                    const float cross = V[4].y - aI * aJ * inv81;
                    const float iv    = V[2].y - aI * aI * inv81;
                    const float jv    = V[3].y - aJ * aJ * inv81;
                    acc.y += cross * cross *
                             __builtin_amdgcn_rcpf(iv * jv + 1e-5f);
                }
            }
        }
        __syncthreads();   // reads of buf R done; DMA(R+1) drained
    }

    // block reduction: wave shuffle, then LDS across the 4 waves
    float sum = acc.x + acc.y;
#pragma unroll
    for (int off = 32; off > 0; off >>= 1) sum += __shfl_down(sum, off, 64);

    if ((t & 63) == 0) wsum[t >> 6] = sum;
    __syncthreads();
    if (t == 0) {
        const float bsum = wsum[0] + wsum[1] + wsum[2] + wsum[3];
        atomicAdd(acc_ws, bsum);          // device-scope
        __threadfence();
        const unsigned old = atomicAdd(cnt_ws, 1u);
        if (old == (unsigned)(NBLOCKS - 1)) {
            const float total = atomicAdd(acc_ws, 0.0f);  // coherent read
            out[0] = -total / 8388608.0f;                 // -mean over 32*512*512
        }
    }
}

extern "C" void kernel_launch(void* const* d_in, const int* in_sizes, int n_in,
                              void* d_out, int out_size, void* d_ws, size_t ws_size,
                              hipStream_t stream) {
    const float* I = (const float*)d_in[0];  // y_true
    const float* J = (const float*)d_in[1];  // y_pred
    float* acc_ws  = (float*)d_ws;           // ws[0]: running sum
    unsigned* cnt  = (unsigned*)d_ws + 1;    // ws[1]: completion counter
    float* out     = (float*)d_out;

    hipMemsetAsync(d_ws, 0, 2 * sizeof(float), stream);

    dim3 grid(NSTRIP, BATCH);
    ncc_main<<<grid, 256, 0, stream>>>(I, J, acc_ws, cnt, out);
}